// Round 1
// baseline (1431.027 us; speedup 1.0000x reference)
//
#include <hip/hip_runtime.h>
#include <hip/hip_bf16.h>

#define GN 16384
#define GD 128
#define KSPLIT 4
#define KBLK (GN / KSPLIT)        // 4096 k per block
#define PHK 128                   // k per LDS phase
#define NPH (KBLK / PHK)          // 32 phases
#define NSTEP (PHK / 32)          // 4 mfma k-steps per phase
#define BUF_SHORTS (GD * PHK)     // 16384 shorts = 32 KB per buffer
#define OUT_ELEMS (GN * GD)
#define GNW (GN / 32)             // 512 bitmask dwords per adj row

typedef __attribute__((ext_vector_type(8))) short short8;
typedef __attribute__((ext_vector_type(4))) float floatx4;
typedef __attribute__((ext_vector_type(4))) int intx4;
typedef __attribute__((ext_vector_type(4))) unsigned uintx4;

static __device__ __forceinline__ unsigned short f32_to_bf16(float f) {
  unsigned u = __builtin_bit_cast(unsigned, f);
  unsigned r = u + 0x7FFFu + ((u >> 16) & 1u);  // RNE (inputs finite/normal)
  return (unsigned short)(r >> 16);
}

// Kernel 1: xT[d][j] <- bf16(x[j][d])  (4 MiB, L2/L3-resident)
__global__ __launch_bounds__(256) void prep_kernel(const float* __restrict__ x,
                                                   unsigned short* __restrict__ xT) {
  __shared__ unsigned short t[GD][66];
  const int tid = threadIdx.x;
  const int j0 = blockIdx.x * 64;
  for (int i = tid; i < 64 * GD; i += 256) {
    int j = i >> 7, d = i & (GD - 1);
    t[d][j] = f32_to_bf16(x[(size_t)(j0 + j) * GD + d]);
  }
  __syncthreads();
  for (int i = tid; i < GD * 32; i += 256) {
    int d = i >> 5, jp = i & 31;
    unsigned lo = t[d][2 * jp], hi = t[d][2 * jp + 1];
    *reinterpret_cast<unsigned*>(xT + (size_t)d * GN + j0 + 2 * jp) = lo | (hi << 16);
  }
}

// Kernel 1b (NEW): bit-pack adj (int32 {0,1}, 1 GiB) -> ubits (32 MiB).
// Pure streaming pass: thread t packs 32 consecutive ints into one dword.
// bit i of ubits[row*GNW + dw] == adj[row][dw*32 + i]. Output coalesced; input
// fully line-covered via per-thread-contiguous 128 B reads (L1 catches the
// 16B-of-64B first touches). Target: ~6 TB/s read => ~175 us.
__global__ __launch_bounds__(256) void pack_kernel(const int* __restrict__ adj,
                                                   unsigned* __restrict__ ubits) {
  const size_t total = (size_t)GN * GNW;  // 8 Mi dwords
  size_t idx = (size_t)blockIdx.x * 256 + threadIdx.x;
  const size_t stride = (size_t)gridDim.x * 256;
  for (; idx < total; idx += stride) {
    const int* p = adj + idx * 32;
    unsigned res = 0;
#pragma unroll
    for (int j = 0; j < 8; ++j) {
      intx4 r = *(const intx4*)(p + j * 4);
      unsigned n = (unsigned)(r.x | (r.y << 1) | (r.z << 2) | (r.w << 3));
      res |= n << (4 * j);
    }
    ubits[idx] = res;
  }
}

// Kernel 2: same MFMA/LDS structure, but A comes from the bitmask.
// Per wave per phase: ONE uintx4 load (4 q-lanes redundant per row; L1/TA
// merges) instead of 8 intx4 of raw adj. Adj register state 64 -> 8 VGPR,
// so acc(32)+bf+staging fit 128 VGPRs with slack. Bit->bf16 expansion is
// ~17 VALU per k-step, reproducing EXACTLY the old af values and k-order:
//   af dword j of step st = bits (st*32 + q*8 + 2j, +2j+1) -> 0x3F80 halves.
__global__ __launch_bounds__(512, 4) void gemm_kernel(const unsigned* __restrict__ ubits,
                                                      const unsigned short* __restrict__ xT,
                                                      float* __restrict__ partials) {
  __shared__ unsigned short bbuf[2][BUF_SHORTS];  // 2 x 32 KB
  const int tid = threadIdx.x;
  const int wave = tid >> 6;
  const int lane = tid & 63;
  const int q = lane >> 4;   // 0..3
  const int m = lane & 15;   // 0..15
  const int rbase = blockIdx.x * 128 + wave * 16;
  const int ks = blockIdx.y;
  const int kbase = ks * KBLK;

  // staging: 4 granules (16 B) per thread; slot s = tid + 512p; row n = s>>4
  const unsigned short* gptr[4];
  unsigned short* lptr[4];
#pragma unroll
  for (int p = 0; p < 4; ++p) {
    int s = tid + 512 * p;            // 0..2047
    int n = s >> 4;                   // B row (= d) 0..127
    int gsrc = (s & 15) ^ (n & 7);    // XOR swizzle (involution on low 3 bits)
    gptr[p] = xT + (size_t)n * GN + kbase + gsrc * 8;
    lptr[p] = &bbuf[0][0] + (size_t)s * 8;
  }

#define STAGE(bufsel, koff)                                                             \
  do {                                                                                  \
    _Pragma("unroll") for (int p = 0; p < 4; ++p) {                                     \
      __builtin_amdgcn_global_load_lds(                                                 \
          (const __attribute__((address_space(1))) unsigned int*)(gptr[p] + (koff)),    \
          (__attribute__((address_space(3))) unsigned int*)(lptr[p] +                   \
                                                           (bufsel) * BUF_SHORTS),      \
          16, 0, 0);                                                                    \
    }                                                                                   \
  } while (0)

  // bitmask row pointer: dwords for this lane's adj row, this k-split slice.
  // phase ph, step st -> dword ub[ph*4 + st]; 16B-aligned (row*512 + ks*128).
  const unsigned* ub = ubits + (size_t)(rbase + m) * GNW + (kbase >> 5);

  floatx4 acc[8];
#pragma unroll
  for (int c = 0; c < 8; ++c) acc[c] = (floatx4){0.f, 0.f, 0.f, 0.f};

  // preload phase 0: staging + the phase's 4 bitmask dwords
  STAGE(0, 0);
  uintx4 cw = *(const uintx4*)(ub);

  int buf = 0;
  for (int ph = 0; ph < NPH; ++ph) {
    __syncthreads();  // staged buf complete; bit loads long since done
    uintx4 nw;
    if (ph + 1 < NPH) {
      STAGE(buf ^ 1, (ph + 1) * PHK);
      nw = *(const uintx4*)(ub + (size_t)(ph + 1) * 4);
    }

#pragma unroll
    for (int st = 0; st < NSTEP; ++st) {
      // B frags: lane(q,m), col-tile cc -> row n=cc*16+m, granule (st*4+q)^(m&7)
      short8 bf[8];
      const unsigned short* bb = &bbuf[buf][0] + (((st * 4 + q) ^ (m & 7)) * 8);
#pragma unroll
      for (int cc = 0; cc < 8; ++cc)
        bf[cc] = *(const short8*)(bb + (cc * 16 + m) * PHK);

      // A frag from bits: byte q of dword st = bits k = st*32 + q*8 + e
      const unsigned w = cw[st];
      const unsigned b = (w >> (q * 8)) & 0xFFu;
      intx4 pk;
#pragma unroll
      for (int j = 0; j < 4; ++j) {
        unsigned t = (b >> (2 * j)) & 3u;                    // bits 2j, 2j+1
        // t*0x8001 puts bit0 at pos0, bit1 at pos16; *0x3F80 -> bf16 1.0 halves
        pk[j] = (int)(((t * 0x8001u) & 0x10001u) * 0x3F80u);
      }
      const short8 af = __builtin_bit_cast(short8, pk);

#pragma unroll
      for (int cc = 0; cc < 8; ++cc)
        acc[cc] = __builtin_amdgcn_mfma_f32_16x16x32_bf16(af, bf[cc], acc[cc], 0, 0, 0);
    }

    cw = nw;
    buf ^= 1;
  }

  // Epilogue: plain stores. C/D: col=lane&15, row=q*4+reg.
  float* pp = partials + (size_t)ks * OUT_ELEMS + (size_t)rbase * GD;
#pragma unroll
  for (int cc = 0; cc < 8; ++cc)
#pragma unroll
    for (int r = 0; r < 4; ++r)
      pp[(size_t)(q * 4 + r) * GD + cc * 16 + m] = acc[cc][r];
}

// Kernel 3: out = x + sum of 4 partials (also un-poisons d_out)
__global__ __launch_bounds__(256) void reduce_kernel(const float* __restrict__ x,
                                                     const float* __restrict__ partials,
                                                     float* __restrict__ out) {
  size_t i = ((size_t)blockIdx.x * 256 + threadIdx.x) * 4;
  floatx4 v = *(const floatx4*)(x + i);
  v += *(const floatx4*)(partials + 0 * (size_t)OUT_ELEMS + i);
  v += *(const floatx4*)(partials + 1 * (size_t)OUT_ELEMS + i);
  v += *(const floatx4*)(partials + 2 * (size_t)OUT_ELEMS + i);
  v += *(const floatx4*)(partials + 3 * (size_t)OUT_ELEMS + i);
  *(floatx4*)(out + i) = v;
}

extern "C" void kernel_launch(void* const* d_in, const int* in_sizes, int n_in,
                              void* d_out, int out_size, void* d_ws, size_t ws_size,
                              hipStream_t stream) {
  const float* x = (const float*)d_in[0];
  const int* adj = (const int*)d_in[1];
  float* out = (float*)d_out;
  unsigned short* xT = (unsigned short*)d_ws;                          // 4 MiB
  float* partials = (float*)((char*)d_ws + (size_t)GN * GD * 2);       // 4 x 8 MiB
  unsigned* ubits = (unsigned*)((char*)d_ws + (size_t)GN * GD * 2 +
                                (size_t)KSPLIT * OUT_ELEMS * 4);       // 32 MiB @ 36 MiB

  prep_kernel<<<GN / 64, 256, 0, stream>>>(x, xT);
  pack_kernel<<<2048, 256, 0, stream>>>(adj, ubits);
  gemm_kernel<<<dim3(GN / 128, KSPLIT), 512, 0, stream>>>(ubits, xT, partials);
  reduce_kernel<<<OUT_ELEMS / 4 / 256, 256, 0, stream>>>(x, partials, out);
}